// Round 1
// baseline (125.719 us; speedup 1.0000x reference)
//
#include <hip/hip_runtime.h>
#include <cstdint>

// Poincare-ball MLR:  out[row][n] = S_n * asinh( lam_row * inner[row][n] * A_n - (lam_row-1) * B_n )
//   inner = X @ Z  (bf16 MFMA),  lam_row = 2/(1 - ||x_row||^2)
//   A_n = cosh(2 r_n)/znorm_n,  B_n = sinh(2 r_n),  S_n = 2 znorm_n   (c = 1)
//
// R6: swapped-operand MFMA epilogue + startup overlap.
// (1) mfma(zfrag, xfrag) instead of mfma(xfrag, zfrag): A/B fragment layouts are
//     identical (lane&15 = spatial idx, quad = k-octet), so D becomes
//     [m=out-col][n=x-row] -> lane&15 = row, reg = 4 CONSECUTIVE out-cols.
//     Epilogue: 8x global_store_dwordx4 per lane (1KB/wave-instr) instead of
//     32 scalar dwords; lam is per-lane (no epilogue shfl). LDS layout, swizzle,
//     staging and X gather unchanged.
// (2) per-col constants as SoA (cA|cB|cS, 3x128 f32) so each lane float4-loads
//     constants for its 4 consecutive columns.
// (3) X HBM loads issued BEFORE Zt staging; ssq+pack before the barrier ->
//     X latency, Zt L2 latency and pack VALU overlap under one vmcnt drain.

typedef __attribute__((ext_vector_type(8))) short short8;   // 8 bf16 = 4 VGPRs (MFMA A/B frag)
typedef __attribute__((ext_vector_type(4))) float floatx4;  // MFMA C/D frag

#define D 128

__device__ inline unsigned bf16_rhu(float f) {   // round-half-up to bf16, bit trick (2 VALU)
    return (__float_as_uint(f) + 0x8000u) >> 16;
}
__device__ inline unsigned pack2(float lo, float hi) {
    return bf16_rhu(lo) | (bf16_rhu(hi) << 16);
}

// ---------------- prep: PRE-SWIZZLED bf16 Zt + SoA per-col constants ----------------
// zt_sw chunk layout: 16B chunk (row, c) stored at chunk index row*16 + (c ^ (row&7)),
// so a linear global_load_lds stage reproduces the swizzled LDS layout.
// cabc layout: cA[128] = cosh(2r)/zn | cB[128] = sinh(2r) | cS[128] = 2*zn*ln2
__global__ void hmlr_prep(const float* __restrict__ z, const float* __restrict__ r,
                          unsigned short* __restrict__ zt_sw, float* __restrict__ cabc) {
    int n = blockIdx.x;
    int k = threadIdx.x;
    float v = z[k * D + n];                          // column n of Z
    int c = k >> 3, p = k & 7;
    zt_sw[n * D + ((c ^ (n & 7)) << 3) + p] = (unsigned short)bf16_rhu(v);
    float pw = v * v;
    #pragma unroll
    for (int off = 32; off >= 1; off >>= 1) pw += __shfl_down(pw, off, 64);
    __shared__ float tmp[2];
    if ((k & 63) == 0) tmp[k >> 6] = pw;
    __syncthreads();
    if (k == 0) {
        float ss = tmp[0] + tmp[1];
        float zn = fmaxf(sqrtf(ss), 1e-15f);
        float tc = 2.0f * r[n];                      // 2*sqrt(c)*r, c=1
        cabc[n]           = coshf(tc) / zn;
        cabc[D + n]       = sinhf(tc);
        cabc[2 * D + n]   = 2.0f * zn * 0.69314718055994531f;   // ln2 folded (asinh via log2)
    }
}

__device__ inline float mlr_elem(float v, float lam, float lm1, float A, float B, float S) {
    float arg = __fmaf_rn(lam * v, A, -lm1 * B);
    float a   = fabsf(arg);
    float as  = __log2f(a + __fsqrt_rn(__fmaf_rn(a, a, 1.0f)));  // asinh/ln2
    return copysignf(as, arg) * S;
}

// ---------------- main: 2048 blocks x 256 threads, 4 waves x 16 rows = 64 rows/block ------
__global__ __launch_bounds__(256, 5) void hmlr_main(const float* __restrict__ x,
                                                    const unsigned short* __restrict__ zt_sw,
                                                    const float* __restrict__ cabc,
                                                    float* __restrict__ out) {
    __shared__ __align__(16) unsigned char lds[32768];   // Zt bf16, swizzled 16B chunks

    const int t    = threadIdx.x;
    const int w    = t >> 6;         // wave 0..3
    const int l    = t & 63;
    const int quad = l >> 4;         // 0..3
    const int l15  = l & 15;
    const int l7   = l & 7;

    // ---- X from global in MFMA frag layout, issued FIRST (HBM latency starts now) ----
    const int rowbase = blockIdx.x * 64 + w * 16;    // this wave's 16 rows
    const float* xrow = x + (size_t)(rowbase + l15) * D + (quad << 3);
    float4 xv[8];
    #pragma unroll
    for (int kc = 0; kc < 4; ++kc) {
        xv[2 * kc]     = *reinterpret_cast<const float4*>(xrow + (kc << 5));
        xv[2 * kc + 1] = *reinterpret_cast<const float4*>(xrow + (kc << 5) + 4);
    }

    // ---- Zt -> LDS: async direct-to-LDS, 1KB per wave-instruction, 8 per wave ----
#if __has_builtin(__builtin_amdgcn_global_load_lds)
    #pragma unroll
    for (int i = 0; i < 8; ++i) {
        int ci = w * 512 + i * 64 + l;               // 16B chunk index 0..2047
        __builtin_amdgcn_global_load_lds(
            (const __attribute__((address_space(1))) unsigned int*)(zt_sw + (ci << 3)),
            (__attribute__((address_space(3))) unsigned int*)(lds + ((w * 512 + i * 64) << 4)),
            16, 0, 0);
    }
#else
    #pragma unroll
    for (int i = 0; i < 8; ++i) {
        int ci = w * 512 + i * 64 + l;
        *reinterpret_cast<uint4*>(&lds[ci << 4]) = reinterpret_cast<const uint4*>(zt_sw)[ci];
    }
#endif

    // ---- ||x_row||^2 fp32 (pre-cast): lane partial + combine quads sharing l15 ----
    // (consumes xv -> overlaps the Zt staging drain; barrier below then costs nothing)
    float ssq = 0.f;
    #pragma unroll
    for (int i = 0; i < 8; ++i)
        ssq += xv[i].x * xv[i].x + xv[i].y * xv[i].y + xv[i].z * xv[i].z + xv[i].w * xv[i].w;
    ssq += __shfl_xor(ssq, 16);
    ssq += __shfl_xor(ssq, 32);      // every lane: ssq of row (rowbase + l15)

    // ---- bf16 X-frags, 2.5 VALU/value bit-trick pack ----
    short8 xfrag[4];
    #pragma unroll
    for (int kc = 0; kc < 4; ++kc) {
        union { short8 s8; unsigned u[4]; } af;
        af.u[0] = pack2(xv[2 * kc].x,     xv[2 * kc].y);
        af.u[1] = pack2(xv[2 * kc].z,     xv[2 * kc].w);
        af.u[2] = pack2(xv[2 * kc + 1].x, xv[2 * kc + 1].y);
        af.u[3] = pack2(xv[2 * kc + 1].z, xv[2 * kc + 1].w);
        xfrag[kc] = af.s8;
    }

    __syncthreads();                 // Zt resident in LDS

    // ---- MFMA 16x16x32 bf16, SWAPPED operands: acc[nt] = Zt_tile(nt) * X ----
    // D layout: lane&15 = n = x-row, quad*4+reg = m = out-col within tile nt.
    floatx4 acc[8];
    #pragma unroll
    for (int nt = 0; nt < 8; ++nt) acc[nt] = (floatx4){0.f, 0.f, 0.f, 0.f};

    #pragma unroll
    for (int kc = 0; kc < 4; ++kc) {
        short8 zf[8];
        #pragma unroll
        for (int nt = 0; nt < 8; ++nt)
            zf[nt] = *reinterpret_cast<const short8*>(
                &lds[((nt * 16 + l15) << 8) + (((quad + (kc << 2)) ^ l7) << 4)]);
        #pragma unroll
        for (int nt = 0; nt < 8; ++nt)
            acc[nt] = __builtin_amdgcn_mfma_f32_16x16x32_bf16(zf[nt], xfrag[kc], acc[nt], 0, 0, 0);
    }

    // ---- epilogue: per-lane row, 4 consecutive cols per float4 -> dwordx4 stores ----
    const float lam = 2.0f / (1.0f - ssq);
    const float lm1 = lam - 1.0f;
    float* orow = out + (size_t)(rowbase + l15) * D + (quad << 2);
    const float4* cAp = reinterpret_cast<const float4*>(cabc);
    const float4* cBp = reinterpret_cast<const float4*>(cabc + D);
    const float4* cSp = reinterpret_cast<const float4*>(cabc + 2 * D);

    #pragma unroll
    for (int nt = 0; nt < 8; ++nt) {
        int cb4 = (nt << 2) + quad;                  // float4 index of cols nt*16+quad*4
        float4 A4 = cAp[cb4];
        float4 B4 = cBp[cb4];
        float4 S4 = cSp[cb4];
        float4 o;
        o.x = mlr_elem(acc[nt][0], lam, lm1, A4.x, B4.x, S4.x);
        o.y = mlr_elem(acc[nt][1], lam, lm1, A4.y, B4.y, S4.y);
        o.z = mlr_elem(acc[nt][2], lam, lm1, A4.z, B4.z, S4.z);
        o.w = mlr_elem(acc[nt][3], lam, lm1, A4.w, B4.w, S4.w);
        *reinterpret_cast<float4*>(orow + (nt << 4)) = o;
    }
}

extern "C" void kernel_launch(void* const* d_in, const int* in_sizes, int n_in,
                              void* d_out, int out_size, void* d_ws, size_t ws_size,
                              hipStream_t stream) {
    const float* x = (const float*)d_in[0];   // [16*8192, 128] fp32
    const float* z = (const float*)d_in[1];   // [128, 128] fp32
    const float* r = (const float*)d_in[2];   // [128] fp32
    float* out = (float*)d_out;

    // ws layout: zt_sw bf16 swizzled [128][128] (32768 B) | cabc f32[3*128] (1536 B)
    char* wsb = (char*)d_ws;
    unsigned short* zt_sw = (unsigned short*)wsb;
    float* cabc = (float*)(wsb + 128 * D * sizeof(unsigned short));

    hmlr_prep<<<128, 128, 0, stream>>>(z, r, zt_sw, cabc);

    const int n_rows = in_sizes[0] / D;       // 131072
    hmlr_main<<<n_rows / 64, 256, 0, stream>>>(x, zt_sw, cabc, out);
}